// Round 1
// baseline (102.575 us; speedup 1.0000x reference)
//
#include <hip/hip_runtime.h>
#include <hip/hip_bf16.h>

#define N 512
#define D 384
#define TILE 32
#define BK 128
#define LDSTRIDE (BK + 4)   // pad: breaks 16-way bank conflict on col-fragment reads

#if __has_builtin(__builtin_amdgcn_exp2f)
#define EXP2F(x) __builtin_amdgcn_exp2f(x)
#else
#define EXP2F(x) exp2f(x)
#endif
#if __has_builtin(__builtin_amdgcn_rcpf)
#define RCPF(x) __builtin_amdgcn_rcpf(x)
#else
#define RCPF(x) (1.0f / (x))
#endif

// Kernel 0: sq[i] = sum_k emb[i][k]^2. One wave (64 lanes) per row.
__global__ __launch_bounds__(256) void sq_kernel(const float* __restrict__ emb,
                                                 float* __restrict__ sq) {
    const int row  = blockIdx.x * 4 + (threadIdx.x >> 6);
    const int lane = threadIdx.x & 63;
    const float* p = emb + row * D;
    float s = 0.f;
#pragma unroll
    for (int i = lane; i < D; i += 64) {  // 6 iters
        float v = p[i];
        s += v * v;
    }
#pragma unroll
    for (int off = 32; off > 0; off >>= 1) s += __shfl_down(s, off);
    if (lane == 0) sq[row] = s;
}

// Kernel 1: dist[r][c] = sqrt(max(sq[r]+sq[c]-2*dot(emb[r],emb[c]), 1e-12)),
// diagonal forced to 1e6. 32x32 output tile per block, LDS-staged GEMM.
__global__ __launch_bounds__(256) void dist_kernel(const float* __restrict__ emb,
                                                   const float* __restrict__ sq,
                                                   float* __restrict__ dist) {
    __shared__ float As[TILE][LDSTRIDE];
    __shared__ float Bs[TILE][LDSTRIDE];
    const int bi = blockIdx.y;   // row tile
    const int bj = blockIdx.x;   // col tile
    const int t  = threadIdx.x;
    const int tc = t & 15;       // col group 0..15
    const int tr = t >> 4;       // row group 0..15
    const int rowBase = bi * TILE;
    const int colBase = bj * TILE;

    float acc00 = 0.f, acc01 = 0.f, acc10 = 0.f, acc11 = 0.f;

    for (int kk = 0; kk < D; kk += BK) {
        // Stage A,B tiles: 32 rows x 128 k-cols each = 1024 float4; 4/thread.
#pragma unroll
        for (int i = 0; i < 4; ++i) {
            int f  = t + i * 256;
            int r  = f >> 5;      // 32 float4 per row (BK/4)
            int c4 = f & 31;
            float4 va = *((const float4*)(emb + (rowBase + r) * D + kk) + c4);
            *((float4*)&As[r][c4 * 4]) = va;
            float4 vb = *((const float4*)(emb + (colBase + r) * D + kk) + c4);
            *((float4*)&Bs[r][c4 * 4]) = vb;
        }
        __syncthreads();
#pragma unroll
        for (int k4 = 0; k4 < BK / 4; ++k4) {
            float4 a0 = *((const float4*)&As[tr][k4 * 4]);
            float4 a1 = *((const float4*)&As[tr + 16][k4 * 4]);
            float4 b0 = *((const float4*)&Bs[tc][k4 * 4]);
            float4 b1 = *((const float4*)&Bs[tc + 16][k4 * 4]);
            acc00 += a0.x * b0.x + a0.y * b0.y + a0.z * b0.z + a0.w * b0.w;
            acc01 += a0.x * b1.x + a0.y * b1.y + a0.z * b1.z + a0.w * b1.w;
            acc10 += a1.x * b0.x + a1.y * b0.y + a1.z * b0.z + a1.w * b0.w;
            acc11 += a1.x * b1.x + a1.y * b1.y + a1.z * b1.z + a1.w * b1.w;
        }
        __syncthreads();
    }

    const int r0 = rowBase + tr, r1 = rowBase + tr + 16;
    const int c0 = colBase + tc, c1 = colBase + tc + 16;
    const float sr0 = sq[r0], sr1 = sq[r1], sc0 = sq[c0], sc1 = sq[c1];

    float d00 = sqrtf(fmaxf(sr0 + sc0 - 2.f * acc00, 1e-12f));
    float d01 = sqrtf(fmaxf(sr0 + sc1 - 2.f * acc01, 1e-12f));
    float d10 = sqrtf(fmaxf(sr1 + sc0 - 2.f * acc10, 1e-12f));
    float d11 = sqrtf(fmaxf(sr1 + sc1 - 2.f * acc11, 1e-12f));
    if (r0 == c0) d00 = 1e6f;
    if (r0 == c1) d01 = 1e6f;
    if (r1 == c0) d10 = 1e6f;
    if (r1 == c1) d11 = 1e6f;
    dist[r0 * N + c0] = d00;
    dist[r0 * N + c1] = d01;
    dist[r1 * N + c0] = d10;
    dist[r1 * N + c1] = d11;
}

// Kernel 2: one block per query q. rank[j] = sum_m sigmoid((d[j]-d[m])/0.01);
// num = sum_j sigmoid(5-rank[j])*gt[j]; den = min(#gt,5); atomicAdd(acc, num/den).
__global__ __launch_bounds__(256) void loss_kernel(const float* __restrict__ dist,
                                                   const int* __restrict__ labels,
                                                   float* __restrict__ acc) {
    const int q = blockIdx.x;
    const int t = threadIdx.x;
    __shared__ float s[N];
    __shared__ float wnum[4], wcnt[4];

    // s[j] = d[q][j] * (1/T2) * log2(e)  so sigmoid((d_j-d_m)/T2) = rcp(1+exp2(s_m-s_j))
    const float C = 144.26950408889634f;  // 100 * log2(e)
    s[t]       = dist[q * N + t] * C;
    s[t + 256] = dist[q * N + t + 256] * C;
    __syncthreads();

    const float s0 = s[t];
    const float s1 = s[t + 256];
    float r0 = 0.f, r1 = 0.f;
#pragma unroll 8
    for (int m = 0; m < N; ++m) {
        float sm = s[m];
        float e0 = EXP2F(sm - s0);
        float e1 = EXP2F(sm - s1);
        r0 += RCPF(1.f + e0);
        r1 += RCPF(1.f + e1);
    }

    const int lq = labels[q];
    const bool g0 = (labels[t] == lq) && (t != q);
    const bool g1 = (labels[t + 256] == lq) && (t + 256 != q);
    const float L2E = 1.4426950408889634f;
    float num = 0.f, cnt = 0.f;
    if (g0) { num += RCPF(1.f + EXP2F((r0 - 5.f) * L2E)); cnt += 1.f; }
    if (g1) { num += RCPF(1.f + EXP2F((r1 - 5.f) * L2E)); cnt += 1.f; }

#pragma unroll
    for (int off = 32; off > 0; off >>= 1) {
        num += __shfl_down(num, off);
        cnt += __shfl_down(cnt, off);
    }
    const int wave = t >> 6, lane = t & 63;
    if (lane == 0) { wnum[wave] = num; wcnt[wave] = cnt; }
    __syncthreads();
    if (t == 0) {
        float tn = wnum[0] + wnum[1] + wnum[2] + wnum[3];
        float tk = wcnt[0] + wcnt[1] + wcnt[2] + wcnt[3];
        float den = fminf(tk, 5.f);
        atomicAdd(acc, tn / den);   // den==0 -> 0/0 = NaN, matches reference
    }
}

// Kernel 3: loss = 1 - mean(precision)
__global__ void final_kernel(const float* __restrict__ acc, float* __restrict__ out) {
    out[0] = 1.0f - acc[0] * (1.0f / 512.0f);
}

extern "C" void kernel_launch(void* const* d_in, const int* in_sizes, int n_in,
                              void* d_out, int out_size, void* d_ws, size_t ws_size,
                              hipStream_t stream) {
    const float* emb   = (const float*)d_in[0];
    const int* labels  = (const int*)d_in[1];
    float* out         = (float*)d_out;
    char* ws           = (char*)d_ws;

    float* dist = (float*)ws;                              // 512*512 floats = 1 MiB
    float* sq   = (float*)(ws + (size_t)N * N * 4);        // 512 floats
    float* acc  = (float*)(ws + (size_t)N * N * 4 + N * 4);// 1 float

    hipMemsetAsync(acc, 0, sizeof(float), stream);
    hipLaunchKernelGGL(sq_kernel,   dim3(N / 4), dim3(256), 0, stream, emb, sq);
    hipLaunchKernelGGL(dist_kernel, dim3(N / TILE, N / TILE), dim3(256), 0, stream, emb, sq, dist);
    hipLaunchKernelGGL(loss_kernel, dim3(N), dim3(256), 0, stream, dist, labels, acc);
    hipLaunchKernelGGL(final_kernel, dim3(1), dim3(1), 0, stream, acc, out);
}

// Round 2
// 74.594 us; speedup vs baseline: 1.3751x; 1.3751x over previous
//
#include <hip/hip_runtime.h>
#include <hip/hip_bf16.h>

#define N 512
#define D 384
#define TILE 32
#define BK 128
#define LDSTRIDE (BK + 4)   // pad breaks power-of-2 bank stride on fragment reads

#if __has_builtin(__builtin_amdgcn_exp2f)
#define EXP2F(x) __builtin_amdgcn_exp2f(x)
#else
#define EXP2F(x) exp2f(x)
#endif
#if __has_builtin(__builtin_amdgcn_rcpf)
#define RCPF(x) __builtin_amdgcn_rcpf(x)
#else
#define RCPF(x) (1.0f / (x))
#endif

// Kernel 1: dist[r][c] = sqrt(max(sum_k (a_k-b_k)^2, 1e-12)), diagonal -> 1e6.
// 32x32 output tile per block, LDS-staged, 2x2 register blocking.
// diff^2 form folds the row-norm (sq) kernel away; rounding diff vs the
// reference's sq-2dot form is ~1e-5 in d, amplified to ~1e-3 in sigmoid args,
// invisible at the 1.96e-2 output threshold.
__global__ __launch_bounds__(256) void dist_kernel(const float* __restrict__ emb,
                                                   float* __restrict__ dist) {
    __shared__ float As[TILE][LDSTRIDE];
    __shared__ float Bs[TILE][LDSTRIDE];
    const int bi = blockIdx.y;
    const int bj = blockIdx.x;
    const int t  = threadIdx.x;
    const int tc = t & 15;
    const int tr = t >> 4;
    const int rowBase = bi * TILE;
    const int colBase = bj * TILE;

    float d00 = 0.f, d01 = 0.f, d10 = 0.f, d11 = 0.f;

    for (int kk = 0; kk < D; kk += BK) {  // 3 iterations
#pragma unroll
        for (int i = 0; i < 4; ++i) {
            int f  = t + i * 256;
            int r  = f >> 5;          // BK/4 = 32 float4 per row
            int c4 = f & 31;
            float4 va = *((const float4*)(emb + (rowBase + r) * D + kk) + c4);
            *((float4*)&As[r][c4 * 4]) = va;
            float4 vb = *((const float4*)(emb + (colBase + r) * D + kk) + c4);
            *((float4*)&Bs[r][c4 * 4]) = vb;
        }
        __syncthreads();
#pragma unroll
        for (int k4 = 0; k4 < BK / 4; ++k4) {
            float4 a0 = *((const float4*)&As[tr][k4 * 4]);
            float4 a1 = *((const float4*)&As[tr + 16][k4 * 4]);
            float4 b0 = *((const float4*)&Bs[tc][k4 * 4]);
            float4 b1 = *((const float4*)&Bs[tc + 16][k4 * 4]);
            float e;
            e = a0.x - b0.x; d00 += e * e;  e = a0.y - b0.y; d00 += e * e;
            e = a0.z - b0.z; d00 += e * e;  e = a0.w - b0.w; d00 += e * e;
            e = a0.x - b1.x; d01 += e * e;  e = a0.y - b1.y; d01 += e * e;
            e = a0.z - b1.z; d01 += e * e;  e = a0.w - b1.w; d01 += e * e;
            e = a1.x - b0.x; d10 += e * e;  e = a1.y - b0.y; d10 += e * e;
            e = a1.z - b0.z; d10 += e * e;  e = a1.w - b0.w; d10 += e * e;
            e = a1.x - b1.x; d11 += e * e;  e = a1.y - b1.y; d11 += e * e;
            e = a1.z - b1.z; d11 += e * e;  e = a1.w - b1.w; d11 += e * e;
        }
        __syncthreads();
    }

    const int r0 = rowBase + tr, r1 = rowBase + tr + 16;
    const int c0 = colBase + tc, c1 = colBase + tc + 16;
    float v00 = sqrtf(fmaxf(d00, 1e-12f));
    float v01 = sqrtf(fmaxf(d01, 1e-12f));
    float v10 = sqrtf(fmaxf(d10, 1e-12f));
    float v11 = sqrtf(fmaxf(d11, 1e-12f));
    if (r0 == c0) v00 = 1e6f;
    if (r0 == c1) v01 = 1e6f;
    if (r1 == c0) v10 = 1e6f;
    if (r1 == c1) v11 = 1e6f;
    dist[r0 * N + c0] = v00;
    dist[r0 * N + c1] = v01;
    dist[r1 * N + c0] = v10;
    dist[r1 * N + c1] = v11;
}

// Kernel 2: one block per query. Soft-rank is only needed for GT columns
// (same label, not self) -- ~8 of 512 -- a 64x transcendental reduction vs
// computing rank for every column. One wave per GT column, lanes parallel
// over the 512-element m-sum.
__global__ __launch_bounds__(256) void loss_kernel(const float* __restrict__ dist,
                                                   const int* __restrict__ labels,
                                                   float* __restrict__ prec) {
    const int q = blockIdx.x;
    const int t = threadIdx.x;
    const int lane = t & 63, wave = t >> 6;
    __shared__ float s[N];
    __shared__ int gt_idx[N];
    __shared__ int gt_n;
    __shared__ float wnum[4];

    if (t == 0) gt_n = 0;
    __syncthreads();

    const int lq = labels[q];
    const float C = 144.26950408889634f;  // (1/T2) * log2(e) = 100*log2(e)
    {
        const int j0 = t, j1 = t + 256;
        s[j0] = dist[q * N + j0] * C;
        s[j1] = dist[q * N + j1] * C;
        if (labels[j0] == lq && j0 != q) { int p = atomicAdd(&gt_n, 1); gt_idx[p] = j0; }
        if (labels[j1] == lq && j1 != q) { int p = atomicAdd(&gt_n, 1); gt_idx[p] = j1; }
    }
    __syncthreads();

    const int n = gt_n;
    float mynum = 0.f;
    // wave-uniform loop: each wave owns GT columns i = wave, wave+4, ...
    for (int i = wave; i < n; i += 4) {
        const float sj = s[gt_idx[i]];
        float r = 0.f;
#pragma unroll
        for (int m = lane; m < N; m += 64) {     // 8 iters; stride-1 LDS (conflict-free)
            r += RCPF(1.f + EXP2F(s[m] - sj));   // sigmoid((d_j - d_m)/T2)
        }
#pragma unroll
        for (int off = 32; off > 0; off >>= 1) r += __shfl_down(r, off);
        if (lane == 0) {
            // sigmoid((K - rank)/T1), T1=1: rcp(1+exp2((rank-5)*log2e))
            mynum += RCPF(1.f + EXP2F((r - 5.f) * 1.4426950408889634f));
        }
    }
    if (lane == 0) wnum[wave] = mynum;
    __syncthreads();
    if (t == 0) {
        float tot = wnum[0] + wnum[1] + wnum[2] + wnum[3];
        float den = fminf((float)n, 5.f);
        prec[q] = tot / den;   // n==0 -> 0/0 = NaN, matches reference
    }
}

// Kernel 3: out = 1 - mean(prec)
__global__ __launch_bounds__(256) void final_kernel(const float* __restrict__ prec,
                                                    float* __restrict__ out) {
    const int t = threadIdx.x;
    const int lane = t & 63, wave = t >> 6;
    __shared__ float w[4];
    float v = prec[t] + prec[t + 256];
#pragma unroll
    for (int off = 32; off > 0; off >>= 1) v += __shfl_down(v, off);
    if (lane == 0) w[wave] = v;
    __syncthreads();
    if (t == 0) out[0] = 1.0f - (w[0] + w[1] + w[2] + w[3]) * (1.0f / 512.0f);
}

extern "C" void kernel_launch(void* const* d_in, const int* in_sizes, int n_in,
                              void* d_out, int out_size, void* d_ws, size_t ws_size,
                              hipStream_t stream) {
    const float* emb  = (const float*)d_in[0];
    const int* labels = (const int*)d_in[1];
    float* out        = (float*)d_out;
    char* ws          = (char*)d_ws;

    float* dist = (float*)ws;                          // 512*512 floats = 1 MiB
    float* prec = (float*)(ws + (size_t)N * N * 4);    // 512 floats

    hipLaunchKernelGGL(dist_kernel, dim3(N / TILE, N / TILE), dim3(256), 0, stream,
                       emb, dist);
    hipLaunchKernelGGL(loss_kernel, dim3(N), dim3(256), 0, stream, dist, labels, prec);
    hipLaunchKernelGGL(final_kernel, dim3(1), dim3(256), 0, stream, prec, out);
}